// Round 15
// baseline (476.279 us; speedup 1.0000x reference)
//
#include <hip/hip_runtime.h>

typedef unsigned short u16;
typedef __attribute__((ext_vector_type(8))) short bf16x8;
typedef __attribute__((ext_vector_type(4))) short bf16x4;
typedef __attribute__((ext_vector_type(4))) float f32x4;
typedef __attribute__((ext_vector_type(4))) unsigned short u16x4;
typedef __attribute__((ext_vector_type(8))) unsigned short u16x8;
typedef __attribute__((ext_vector_type(4))) int i32x4;
typedef __attribute__((ext_vector_type(4))) float f4;

#define DI __device__ __forceinline__

// B=8, Q=100, C=1024, K=4096, NH=16, HD=64, SCALE=0.125

DI u16 f2bf(float f){
  unsigned int u = __float_as_uint(f);
  return (u16)((u + 0x7FFFu + ((u >> 16) & 1u)) >> 16);
}

DI void gl_lds16(const void* g, void* l){
  __builtin_amdgcn_global_load_lds((const __attribute__((address_space(1))) unsigned int*)g,
                                   (__attribute__((address_space(3))) unsigned int*)l, 16, 0, 0);
}

// ---------------- fused prep: blocks 0..4095 = kv (R4 form), 4096..8991 = q/W ----------------
__global__ __launch_bounds__(256) void prep_all(const float* __restrict__ mem,
                                                const float* __restrict__ mpos,
                                                const float* __restrict__ tgt,
                                                const float* __restrict__ qpos,
                                                const float* __restrict__ Wq, const float* __restrict__ Wk,
                                                const float* __restrict__ Wv, const float* __restrict__ Wo,
                                                u16* __restrict__ kA, u16* __restrict__ vA,
                                                u16* __restrict__ qA, u16* __restrict__ Wbf){
  if (blockIdx.x < 4096){
    const int t = blockIdx.x * 256 + threadIdx.x;      // 1,048,576 threads
    #pragma unroll
    for (int i = 0; i < 4; ++i){
      const size_t g = (size_t)t + (size_t)i * 1048576; // 8-float group id, 4,194,304 total
      f4 m0 = __builtin_nontemporal_load((const f4*)mem  + g * 2);
      f4 m1 = __builtin_nontemporal_load((const f4*)mem  + g * 2 + 1);
      f4 p0 = __builtin_nontemporal_load((const f4*)mpos + g * 2);
      f4 p1 = __builtin_nontemporal_load((const f4*)mpos + g * 2 + 1);
      u16x8 k, v;
      #pragma unroll
      for (int j = 0; j < 4; ++j){
        k[j]     = f2bf(m0[j] + p0[j]);  v[j]     = f2bf(m0[j]);
        k[j + 4] = f2bf(m1[j] + p1[j]);  v[j + 4] = f2bf(m1[j]);
      }
      ((u16x8*)kA)[g] = k;
      ((u16x8*)vA)[g] = v;
    }
  } else {
    int gid = (blockIdx.x - 4096) * 256 + threadIdx.x;  // 4896*256 = 1,253,376
    const int NQ4 = 819200 / 4;                // 204800
    if (gid < NQ4){
      f4 a = ((const f4*)tgt)[gid];
      f4 b = ((const f4*)qpos)[gid];
      u16x4 r;
      #pragma unroll
      for (int j = 0; j < 4; ++j) r[j] = f2bf(a[j] + b[j]);
      ((u16x4*)qA)[gid] = r;
    } else {
      int wid = gid - NQ4;                     // 0..1048575
      int sel = wid >> 18;                     // /262144
      int off = wid & 262143;
      const float* W = (sel == 0) ? Wq : (sel == 1) ? Wk : (sel == 2) ? Wv : Wo;
      f4 w = ((const f4*)W)[off];
      u16x4 r;
      #pragma unroll
      for (int j = 0; j < 4; ++j) r[j] = f2bf(w[j]);
      ((u16x4*)(Wbf))[(size_t)sel * 262144 + off] = r;
    }
  }
}

// ---------------- 128x128 GEMM, fragment-linear LDS (conflict-free), multi-block/CU ----------------
// m97-family: BK=32, 2-phase __syncthreads, 32KB LDS -> 3+ blocks/CU (m114 overlap:
// one block's LDS reads run under another block's MFMA). Fragment-linear subtiles
// (R6-verified): stage = per-wave 1KB subtile, gl_lds linear dest + permuted global
// src (lane l <-> row sb*16+(l&15), k-chunk (l>>4)*8); read = subtile base + l*16
// (contiguous 1KB wave stream, 0 bank conflicts; R1's layout cost 8.4M conflict-cyc).
// MODE 0: bf16 out = acc*scale.   MODE 1: f32 out = acc + bias[col] + resid[row,col].
template<int MODE>
__global__ __launch_bounds__(256, 2) void gemm_bt(
    const u16* __restrict__ A, const u16* __restrict__ Bw,
    u16* __restrict__ Cb, float* __restrict__ Cf,
    const float* __restrict__ bias, const float* __restrict__ resid,
    int M, float scale)
{
  __shared__ __align__(16) u16 lA[2][8 * 512];   // [buf][8 subtiles][1024B]
  __shared__ __align__(16) u16 lB[2][8 * 512];
  const int tid = threadIdx.x;
  const int l = tid & 63, w = tid >> 6;
  const int nwg = gridDim.x;
  int bid = blockIdx.x;
  bid = (bid & 7) * (nwg >> 3) + (bid >> 3);   // XCD swizzle (nwg % 8 == 0 always)
  const int mb = bid >> 3, nb = bid & 7;
  const int m0 = mb * 128, n0 = nb * 128;
  const int fr = l & 15, fg = l >> 4;
  const int wr = w >> 1, wc = w & 1;

  f32x4 acc[4][4] = {};

  // stage: wave w fills subtiles w*2, w*2+1 of each operand (16 rows x 32 cols each)
  auto stage = [&](int buf, int kt){
    const int k0 = kt * 32 + fg * 8;
    #pragma unroll
    for (int q = 0; q < 2; ++q){
      const int sb = w * 2 + q;
      int ar = m0 + sb * 16 + fr; if (ar >= M) ar = M - 1;
      gl_lds16(A  + (size_t)ar * 1024 + k0, &lA[buf][sb * 512]);
      gl_lds16(Bw + (size_t)(n0 + sb * 16 + fr) * 1024 + k0, &lB[buf][sb * 512]);
    }
  };

  stage(0, 0);
  __syncthreads();
  for (int kt = 0; kt < 32; ++kt){
    const int cur = kt & 1;
    if (kt < 31) stage(cur ^ 1, kt + 1);
    bf16x8 av[4], bv[4];
    #pragma unroll
    for (int m = 0; m < 4; ++m)
      av[m] = *(const bf16x8*)((const char*)&lA[cur][(wr * 4 + m) * 512] + l * 16);
    #pragma unroll
    for (int n = 0; n < 4; ++n)
      bv[n] = *(const bf16x8*)((const char*)&lB[cur][(wc * 4 + n) * 512] + l * 16);
    #pragma unroll
    for (int m = 0; m < 4; ++m)
      #pragma unroll
      for (int n = 0; n < 4; ++n)
        acc[m][n] = __builtin_amdgcn_mfma_f32_16x16x32_bf16(av[m], bv[n], acc[m][n], 0, 0, 0);
    __syncthreads();
  }

  #pragma unroll
  for (int m = 0; m < 4; ++m){
    const int grow_base = m0 + wr * 64 + m * 16 + fg * 4;
    #pragma unroll
    for (int n = 0; n < 4; ++n){
      const int gcol = n0 + wc * 64 + n * 16 + fr;
      #pragma unroll
      for (int r = 0; r < 4; ++r){
        const int grow = grow_base + r;
        if (grow < M){
          const float v = acc[m][n][r];
          if (MODE == 0) Cb[(size_t)grow * 1024 + gcol] = f2bf(v * scale);
          else           Cf[(size_t)grow * 1024 + gcol] = v + bias[gcol] + resid[(size_t)grow * 1024 + gcol];
        }
      }
    }
  }
}

// ---------------- attention (R10 version: single wave, reg-staged V, replay-proven) ----------------
__global__ __launch_bounds__(64, 1) void attn_k(
    const u16* __restrict__ qp, const u16* __restrict__ kp, const u16* __restrict__ vp,
    float* __restrict__ updpart, float* __restrict__ rspart)
{
  const int bidx = blockIdx.x;
  const int c = bidx & 7, h = (bidx >> 3) & 15, b = bidx >> 7;
  const int bh = b * 16 + h;
  const int l = threadIdx.x;
  const int fr = l & 15, fg = l >> 4;

  __shared__ u16 qlds[112 * 64];
  __shared__ __align__(16) u16 vlds[2][16 * 64];   // [buf][key row 0..15][dim 0..63]

  for (int t = 0; t < 14; ++t){
    int chunk = t * 64 + l;            // 0..895
    int row = chunk >> 3, cb = chunk & 7;
    i32x4 val = {0, 0, 0, 0};
    if (row < 100)
      val = *(const i32x4*)(qp + (size_t)(b * 100 + row) * 1024 + h * 64 + cb * 8);
    *(i32x4*)((char*)qlds + row * 128 + ((cb ^ (row & 7)) * 16)) = val;
  }
  __syncthreads();

  bf16x8 qf[7][2];
  #pragma unroll
  for (int n = 0; n < 7; ++n)
    #pragma unroll
    for (int ks = 0; ks < 2; ++ks){
      int row = n * 16 + fr;
      int cb = ks * 4 + fg;
      qf[n][ks] = *(const bf16x8*)((const char*)qlds + row * 128 + ((cb ^ (row & 7)) * 16));
    }

  f32x4 acc[7][4] = {};
  float rs[7] = {};
  const f32x4 fz = {0.f, 0.f, 0.f, 0.f};
  const size_t kvbase = ((size_t)b * 4096) * 1024 + h * 64;
  const int j00 = c * 512;

  const u16* ksrc = kp + kvbase + (size_t)fr * 1024 + fg * 8;
  const u16* vsrc = vp + kvbase + (size_t)(l >> 3) * 1024 + (l & 7) * 8;  // row l>>3, chunk l&7

  auto loadK = [&](int t, bf16x8& k0, bf16x8& k1){
    const size_t ro = (size_t)(j00 + t * 16) * 1024;
    k0 = *(const bf16x8*)(ksrc + ro);
    k1 = *(const bf16x8*)(ksrc + ro + 32);
  };
  auto loadV = [&](int t, bf16x8& a, bf16x8& bb){
    const size_t ro = (size_t)(j00 + t * 16) * 1024;
    a  = *(const bf16x8*)(vsrc + ro);             // rows 0..7 of tile
    bb = *(const bf16x8*)(vsrc + ro + 8 * 1024);  // rows 8..15
  };
  auto writeV = [&](int buf, bf16x8 a, bf16x8 bb){
    *(bf16x8*)&vlds[buf][l * 8] = a;
    *(bf16x8*)&vlds[buf][512 + l * 8] = bb;
  };

  bf16x8 kc0, kc1, kn0, kn1, vn0, vn1;
  loadK(0, kc0, kc1);
  loadV(0, vn0, vn1);
  writeV(0, vn0, vn1);

  for (int t = 0; t < 32; ++t){
    const int cur = t & 1;
    if (t < 31){
      loadK(t + 1, kn0, kn1);     // issue early; latency hides under QK+softmax+PV
      loadV(t + 1, vn0, vn1);
    }

    f32x4 s[7];
    #pragma unroll
    for (int n = 0; n < 7; ++n){
      s[n] = __builtin_amdgcn_mfma_f32_16x16x32_bf16(kc0, qf[n][0], fz, 0, 0, 0);
      s[n] = __builtin_amdgcn_mfma_f32_16x16x32_bf16(kc1, qf[n][1], s[n], 0, 0, 0);
    }
    if (fr >= 4){ s[6][0] = -1e30f; s[6][1] = -1e30f; s[6][2] = -1e30f; s[6][3] = -1e30f; }

    float pv[7][4];
    #pragma unroll
    for (int r = 0; r < 4; ++r){
      float m = s[0][r];
      #pragma unroll
      for (int n = 1; n < 7; ++n) m = fmaxf(m, s[n][r]);
      m = fmaxf(m, __shfl_xor(m, 1)); m = fmaxf(m, __shfl_xor(m, 2));
      m = fmaxf(m, __shfl_xor(m, 4)); m = fmaxf(m, __shfl_xor(m, 8));
      float sum = 0.f;
      #pragma unroll
      for (int n = 0; n < 7; ++n){ float e = __expf(s[n][r] - m); pv[n][r] = e; sum += e; }
      sum += __shfl_xor(sum, 1); sum += __shfl_xor(sum, 2);
      sum += __shfl_xor(sum, 4); sum += __shfl_xor(sum, 8);
      float inv = 1.0f / sum;
      #pragma unroll
      for (int n = 0; n < 7; ++n) pv[n][r] *= inv;
    }

    bf16x4 pk[7];
    #pragma unroll
    for (int n = 0; n < 7; ++n){
      rs[n] += pv[n][0] + pv[n][1] + pv[n][2] + pv[n][3];
      bf16x4 t4;
      t4[0] = (short)f2bf(pv[n][0]); t4[1] = (short)f2bf(pv[n][1]);
      t4[2] = (short)f2bf(pv[n][2]); t4[3] = (short)f2bf(pv[n][3]);
      pk[n] = t4;
    }

    bf16x4 vf[4];
    #pragma unroll
    for (int dt = 0; dt < 4; ++dt){
      bf16x4 tv;
      #pragma unroll
      for (int jj = 0; jj < 4; ++jj)
        tv[jj] = (short)vlds[cur][(fg * 4 + jj) * 64 + dt * 16 + fr];
      vf[dt] = tv;
    }

    #pragma unroll
    for (int n = 0; n < 7; ++n)
      #pragma unroll
      for (int dt = 0; dt < 4; ++dt)
        acc[n][dt] = __builtin_amdgcn_mfma_f32_16x16x16bf16_1k(vf[dt], pk[n], acc[n][dt], 0, 0, 0);

    if (t < 31){
      writeV(cur ^ 1, vn0, vn1);   // after PV reads of vlds[cur]; other buffer anyway
      kc0 = kn0; kc1 = kn1;
    }
  }

  #pragma unroll
  for (int n = 0; n < 7; ++n){
    float v = rs[n];
    v += __shfl_xor(v, 16); v += __shfl_xor(v, 32);
    if (l < 16) rspart[((size_t)c * 128 + bh) * 112 + n * 16 + l] = v;
  }
  float* ub = updpart + ((size_t)c * 128 + bh) * 64 * 112;
  #pragma unroll
  for (int n = 0; n < 7; ++n)
    #pragma unroll
    for (int dt = 0; dt < 4; ++dt)
      #pragma unroll
      for (int r = 0; r < 4; ++r){
        int d = dt * 16 + fg * 4 + r;
        int i = n * 16 + fr;
        ub[d * 112 + i] = acc[n][dt][r];
      }
}

// ---------------- reduce partials (transposed: coalesced reads) ----------------
__global__ __launch_bounds__(128) void nrm_k(const float* __restrict__ updpart,
                                             const float* __restrict__ rspart,
                                             u16* __restrict__ updn){
  const int bid = blockIdx.x;
  const int d = bid & 63, h = (bid >> 6) & 15, b = bid >> 10;
  const int bh = b * 16 + h;
  const int tid = threadIdx.x;
  const int i = (tid < 112) ? tid : 111;
  float sum = 0.f, rsum = 0.f;
  #pragma unroll
  for (int cc = 0; cc < 8; ++cc){
    sum  += updpart[(((size_t)cc * 128 + bh) * 64 + d) * 112 + i];
    rsum += rspart[((size_t)cc * 128 + bh) * 112 + i];
  }
  if (tid < 100)
    updn[((size_t)b * 100 + tid) * 1024 + h * 64 + d] = f2bf(sum / (rsum + 1e-8f));
}

// ---------------- LayerNorm over rows of resid [800 x 1024] ----------------
__global__ __launch_bounds__(256) void ln_k(const float* __restrict__ x,
                                            const float* __restrict__ g,
                                            const float* __restrict__ be,
                                            float* __restrict__ out){
  const int row = blockIdx.x;
  const int tid = threadIdx.x;
  const f4 xv = *(const f4*)(x + (size_t)row * 1024 + tid * 4);
  float s = xv[0] + xv[1] + xv[2] + xv[3];
  float q = xv[0]*xv[0] + xv[1]*xv[1] + xv[2]*xv[2] + xv[3]*xv[3];
  #pragma unroll
  for (int m = 1; m < 64; m <<= 1){ s += __shfl_xor(s, m); q += __shfl_xor(q, m); }
  __shared__ float ss[4], qq[4];
  const int w = tid >> 6;
  if ((tid & 63) == 0){ ss[w] = s; qq[w] = q; }
  __syncthreads();
  s = ss[0] + ss[1] + ss[2] + ss[3];
  q = qq[0] + qq[1] + qq[2] + qq[3];
  const float mu = s * (1.0f / 1024.0f);
  const float var = q * (1.0f / 1024.0f) - mu * mu;
  const float rstd = rsqrtf(var + 1e-5f);
  const f4 gv = *(const f4*)(g + tid * 4);
  const f4 bv = *(const f4*)(be + tid * 4);
  f4 o;
  #pragma unroll
  for (int j = 0; j < 4; ++j) o[j] = (xv[j] - mu) * rstd * gv[j] + bv[j];
  *(f4*)(out + (size_t)row * 1024 + tid * 4) = o;
}

extern "C" void kernel_launch(void* const* d_in, const int* in_sizes, int n_in,
                              void* d_out, int out_size, void* d_ws, size_t ws_size,
                              hipStream_t stream)
{
  const float* tgt   = (const float*)d_in[0];
  const float* mem   = (const float*)d_in[1];
  const float* mpos  = (const float*)d_in[2];
  const float* qpos  = (const float*)d_in[3];
  const float* Wq    = (const float*)d_in[4];
  const float* Wk    = (const float*)d_in[5];
  const float* Wv    = (const float*)d_in[6];
  const float* Wo    = (const float*)d_in[7];
  const float* bo    = (const float*)d_in[8];
  const float* gamma = (const float*)d_in[9];
  const float* beta  = (const float*)d_in[10];

  char* ws = (char*)d_ws;
  u16* qA     = (u16*)(ws + 0);
  u16* Wbf    = (u16*)(ws + 1638400);
  u16* kA     = (u16*)(ws + 10027008);
  u16* vA     = (u16*)(ws + 77135872);
  u16* qproj  = (u16*)(ws + 144244736);
  u16* kproj  = (u16*)(ws + 145883136);
  u16* vproj  = kA;                                   // kA dead after K-GEMM (serialized)
  float* updpart = (float*)(ws + 77135872);           // vA dead after V-GEMM
  float* rspart  = (float*)(ws + 77135872 + 29360128);
  u16*   updn    = (u16*)  (ws + 77135872 + 29818880);
  float* resid   = (float*)(ws + 77135872 + 31457280);

  prep_all<<<8992, 256, 0, stream>>>(mem, mpos, tgt, qpos, Wq, Wk, Wv, Wo, kA, vA, qA, Wbf);
  gemm_bt<0><<<56,   256, 0, stream>>>(qA, Wbf, qproj, nullptr, nullptr, nullptr, 800, 0.125f);
  gemm_bt<0><<<2048, 256, 0, stream>>>(kA, Wbf + 1048576, kproj, nullptr, nullptr, nullptr, 32768, 1.0f);
  gemm_bt<0><<<2048, 256, 0, stream>>>(vA, Wbf + 2097152, vproj, nullptr, nullptr, nullptr, 32768, 1.0f);
  attn_k<<<1024, 64, 0, stream>>>(qproj, kproj, vproj, updpart, rspart);
  nrm_k<<<8192, 128, 0, stream>>>(updpart, rspart, updn);
  gemm_bt<1><<<56, 256, 0, stream>>>(updn, Wbf + 3145728, nullptr, resid, bo, tgt, 800, 1.0f);
  ln_k<<<800, 256, 0, stream>>>(resid, gamma, beta, (float*)d_out);
}

// Round 16
// 377.407 us; speedup vs baseline: 1.2620x; 1.2620x over previous
//
#include <hip/hip_runtime.h>

typedef unsigned short u16;
typedef __attribute__((ext_vector_type(8))) short bf16x8;
typedef __attribute__((ext_vector_type(4))) short bf16x4;
typedef __attribute__((ext_vector_type(4))) float f32x4;
typedef __attribute__((ext_vector_type(4))) unsigned short u16x4;
typedef __attribute__((ext_vector_type(8))) unsigned short u16x8;
typedef __attribute__((ext_vector_type(4))) int i32x4;
typedef __attribute__((ext_vector_type(4))) float f4;

#define DI __device__ __forceinline__

// B=8, Q=100, C=1024, K=4096, NH=16, HD=64, SCALE=0.125

DI u16 f2bf(float f){
  unsigned int u = __float_as_uint(f);
  return (u16)((u + 0x7FFFu + ((u >> 16) & 1u)) >> 16);
}

DI void gl_lds16(const void* g, void* l){
  __builtin_amdgcn_global_load_lds((const __attribute__((address_space(1))) unsigned int*)g,
                                   (__attribute__((address_space(3))) unsigned int*)l, 16, 0, 0);
}

// ---------------- fused prep: blocks 0..4095 = kv (R4 form), 4096..8991 = q/W ----------------
__global__ __launch_bounds__(256) void prep_all(const float* __restrict__ mem,
                                                const float* __restrict__ mpos,
                                                const float* __restrict__ tgt,
                                                const float* __restrict__ qpos,
                                                const float* __restrict__ Wq, const float* __restrict__ Wk,
                                                const float* __restrict__ Wv, const float* __restrict__ Wo,
                                                u16* __restrict__ kA, u16* __restrict__ vA,
                                                u16* __restrict__ qA, u16* __restrict__ Wbf){
  if (blockIdx.x < 4096){
    const int t = blockIdx.x * 256 + threadIdx.x;      // 1,048,576 threads
    #pragma unroll
    for (int i = 0; i < 4; ++i){
      const size_t g = (size_t)t + (size_t)i * 1048576; // 8-float group id, 4,194,304 total
      f4 m0 = __builtin_nontemporal_load((const f4*)mem  + g * 2);
      f4 m1 = __builtin_nontemporal_load((const f4*)mem  + g * 2 + 1);
      f4 p0 = __builtin_nontemporal_load((const f4*)mpos + g * 2);
      f4 p1 = __builtin_nontemporal_load((const f4*)mpos + g * 2 + 1);
      u16x8 k, v;
      #pragma unroll
      for (int j = 0; j < 4; ++j){
        k[j]     = f2bf(m0[j] + p0[j]);  v[j]     = f2bf(m0[j]);
        k[j + 4] = f2bf(m1[j] + p1[j]);  v[j + 4] = f2bf(m1[j]);
      }
      ((u16x8*)kA)[g] = k;
      ((u16x8*)vA)[g] = v;
    }
  } else {
    int gid = (blockIdx.x - 4096) * 256 + threadIdx.x;  // 4896*256 = 1,253,376
    const int NQ4 = 819200 / 4;                // 204800
    if (gid < NQ4){
      f4 a = ((const f4*)tgt)[gid];
      f4 b = ((const f4*)qpos)[gid];
      u16x4 r;
      #pragma unroll
      for (int j = 0; j < 4; ++j) r[j] = f2bf(a[j] + b[j]);
      ((u16x4*)qA)[gid] = r;
    } else {
      int wid = gid - NQ4;                     // 0..1048575
      int sel = wid >> 18;                     // /262144
      int off = wid & 262143;
      const float* W = (sel == 0) ? Wq : (sel == 1) ? Wk : (sel == 2) ? Wv : Wo;
      f4 w = ((const f4*)W)[off];
      u16x4 r;
      #pragma unroll
      for (int j = 0; j < 4; ++j) r[j] = f2bf(w[j]);
      ((u16x4*)(Wbf))[(size_t)sel * 262144 + off] = r;
    }
  }
}

// ---------------- 256x256 8-wave GEMM (R7/R12 4-phase version, replay-proven) ----------------
DI void gemm256_body(const u16* __restrict__ A, const u16* __restrict__ Bw,
                     u16* __restrict__ Cb, float scale, int sbid, int tid, char* lds)
{
  const int l = tid & 63, w = tid >> 6;
  const int mb = sbid >> 2, nb = sbid & 3;
  const int m0 = mb * 256, n0 = nb * 256;
  const int fr = l & 15, fg = l >> 4;
  const int wm = w >> 2, wn = w & 3;

  char* ldsA  = lds + wm * 8192 + l * 16;
  char* ldsB  = lds + 32768 + wn * 4096 + l * 16;
  char* ldsS0 = lds + w * 1024;
  char* ldsS1 = lds + (8 + w) * 1024;
  const u16* gA0 = A  + (size_t)(m0 + w * 16 + fr) * 1024 + fg * 8;
  const u16* gA1 = A  + (size_t)(m0 + (8 + w) * 16 + fr) * 1024 + fg * 8;
  const u16* gB0 = Bw + (size_t)(n0 + w * 16 + fr) * 1024 + fg * 8;
  const u16* gB1 = Bw + (size_t)(n0 + (8 + w) * 16 + fr) * 1024 + fg * 8;

  auto stA = [&](int pp, int kh, int kt){
    const int o = kt * 64 + kh * 32;
    gl_lds16(gA0 + o, ldsS0 + pp * 65536 + kh * 16384);
    gl_lds16(gA1 + o, ldsS1 + pp * 65536 + kh * 16384);
  };
  auto stB = [&](int pp, int kh, int kt){
    const int o = kt * 64 + kh * 32;
    gl_lds16(gB0 + o, ldsS0 + pp * 65536 + 32768 + kh * 16384);
    gl_lds16(gB1 + o, ldsS1 + pp * 65536 + 32768 + kh * 16384);
  };
  auto rdA4 = [&](bf16x8* av, int pp, int kh, int mfb){
    #pragma unroll
    for (int i = 0; i < 4; ++i)
      av[i] = *(const bf16x8*)(ldsA + pp * 65536 + kh * 16384 + (mfb + i) * 1024);
  };
  auto rdB4 = [&](bf16x8* bv, int pp, int kh){
    #pragma unroll
    for (int i = 0; i < 4; ++i)
      bv[i] = *(const bf16x8*)(ldsB + pp * 65536 + kh * 16384 + i * 1024);
  };

  f32x4 acc[8][4] = {};

  stA(0, 0, 0); stB(0, 0, 0); stA(0, 1, 0); stB(0, 1, 0);
  stA(1, 0, 1); stB(1, 0, 1);
  asm volatile("s_waitcnt vmcnt(8)" ::: "memory");
  __builtin_amdgcn_s_barrier();

  auto ktbody = [&](int P, int kt){
    const int kt1 = (kt + 1 > 15) ? 15 : kt + 1;
    const int kt2 = (kt + 2 > 15) ? 15 : kt + 2;
    bf16x8 av[4], bv[4];

    rdA4(av, P, 0, 0); rdB4(bv, P, 0);
    stA(P ^ 1, 1, kt1);
    __builtin_amdgcn_s_barrier();
    __builtin_amdgcn_s_setprio(1);
    #pragma unroll
    for (int i = 0; i < 4; ++i)
      #pragma unroll
      for (int n = 0; n < 4; ++n)
        acc[i][n] = __builtin_amdgcn_mfma_f32_16x16x32_bf16(av[i], bv[n], acc[i][n], 0, 0, 0);
    __builtin_amdgcn_s_setprio(0);
    __builtin_amdgcn_s_barrier();

    rdA4(av, P, 0, 4);
    stB(P ^ 1, 1, kt1);
    asm volatile("s_waitcnt vmcnt(8)" ::: "memory");
    __builtin_amdgcn_s_barrier();
    __builtin_amdgcn_s_setprio(1);
    #pragma unroll
    for (int i = 0; i < 4; ++i)
      #pragma unroll
      for (int n = 0; n < 4; ++n)
        acc[4 + i][n] = __builtin_amdgcn_mfma_f32_16x16x32_bf16(av[i], bv[n], acc[4 + i][n], 0, 0, 0);
    __builtin_amdgcn_s_setprio(0);
    __builtin_amdgcn_s_barrier();

    rdA4(av, P, 1, 0); rdB4(bv, P, 1);
    stA(P, 0, kt2);
    __builtin_amdgcn_s_barrier();
    __builtin_amdgcn_s_setprio(1);
    #pragma unroll
    for (int i = 0; i < 4; ++i)
      #pragma unroll
      for (int n = 0; n < 4; ++n)
        acc[i][n] = __builtin_amdgcn_mfma_f32_16x16x32_bf16(av[i], bv[n], acc[i][n], 0, 0, 0);
    __builtin_amdgcn_s_setprio(0);
    __builtin_amdgcn_s_barrier();

    rdA4(av, P, 1, 4);
    stB(P, 0, kt2);
    asm volatile("s_waitcnt vmcnt(8)" ::: "memory");
    __builtin_amdgcn_s_barrier();
    __builtin_amdgcn_s_setprio(1);
    #pragma unroll
    for (int i = 0; i < 4; ++i)
      #pragma unroll
      for (int n = 0; n < 4; ++n)
        acc[4 + i][n] = __builtin_amdgcn_mfma_f32_16x16x32_bf16(av[i], bv[n], acc[4 + i][n], 0, 0, 0);
    __builtin_amdgcn_s_setprio(0);
    __builtin_amdgcn_s_barrier();
  };

  for (int kk = 0; kk < 8; ++kk){
    ktbody(0, 2 * kk);
    ktbody(1, 2 * kk + 1);
  }

  asm volatile("s_waitcnt vmcnt(0)" ::: "memory");

  #pragma unroll
  for (int mf = 0; mf < 8; ++mf){
    #pragma unroll
    for (int nf = 0; nf < 4; ++nf){
      const int gcol = n0 + wn * 64 + nf * 16 + fr;
      #pragma unroll
      for (int r = 0; r < 4; ++r){
        const int grow = m0 + wm * 128 + mf * 16 + fg * 4 + r;
        Cb[(size_t)grow * 1024 + gcol] = f2bf(acc[mf][nf][r] * scale);
      }
    }
  }
}

__global__ __launch_bounds__(512, 1) void gemm256(
    const u16* __restrict__ A, const u16* __restrict__ Bw, u16* __restrict__ Cb)
{
  __shared__ __align__(16) char lds[131072];
  const int nwg = gridDim.x;
  const int sbid = (blockIdx.x & 7) * (nwg >> 3) + (blockIdx.x >> 3);
  gemm256_body(A, Bw, Cb, 1.0f, sbid, threadIdx.x, lds);
}

// ---------------- 128x128 GEMM (small M; R1 coalesced-stage layout) ----------------
template<int MODE>
__global__ __launch_bounds__(256, 2) void gemm_bt(
    const u16* __restrict__ A, const u16* __restrict__ Bw,
    u16* __restrict__ Cb, float* __restrict__ Cf,
    const float* __restrict__ bias, const float* __restrict__ resid,
    int M, float scale)
{
  __shared__ u16 lA[2][128 * 32];
  __shared__ u16 lB[2][128 * 32];
  const int tid = threadIdx.x;
  const int l = tid & 63, w = tid >> 6;
  const int nwg = gridDim.x;
  int bid = blockIdx.x;
  bid = (bid & 7) * (nwg >> 3) + (bid >> 3);   // XCD swizzle (nwg % 8 == 0 always)
  const int mb = bid >> 3, nb = bid & 7;
  const int m0 = mb * 128, n0 = nb * 128;
  const int fr = l & 15, fg = l >> 4;
  const int wr = w >> 1, wc = w & 1;

  f32x4 acc[4][4] = {};

  auto stage = [&](int buf, int kt){
    const int k0 = kt * 32;
    #pragma unroll
    for (int q = 0; q < 2; ++q){
      int r = w * 32 + q * 16 + (l >> 2);
      int ar = m0 + r; if (ar >= M) ar = M - 1;
      gl_lds16(A  + (size_t)ar * 1024 + k0 + (l & 3) * 8, &lA[buf][(w * 32 + q * 16) * 32]);
      gl_lds16(Bw + (size_t)(n0 + r) * 1024 + k0 + (l & 3) * 8, &lB[buf][(w * 32 + q * 16) * 32]);
    }
  };

  stage(0, 0);
  __syncthreads();
  for (int kt = 0; kt < 32; ++kt){
    const int cur = kt & 1;
    if (kt < 31) stage(cur ^ 1, kt + 1);
    bf16x8 av[4], bv[4];
    #pragma unroll
    for (int m = 0; m < 4; ++m)
      av[m] = *(const bf16x8*)&lA[cur][(wr * 64 + m * 16 + fr) * 32 + fg * 8];
    #pragma unroll
    for (int n = 0; n < 4; ++n)
      bv[n] = *(const bf16x8*)&lB[cur][(wc * 64 + n * 16 + fr) * 32 + fg * 8];
    #pragma unroll
    for (int m = 0; m < 4; ++m)
      #pragma unroll
      for (int n = 0; n < 4; ++n)
        acc[m][n] = __builtin_amdgcn_mfma_f32_16x16x32_bf16(av[m], bv[n], acc[m][n], 0, 0, 0);
    __syncthreads();
  }

  #pragma unroll
  for (int m = 0; m < 4; ++m){
    const int grow_base = m0 + wr * 64 + m * 16 + fg * 4;
    #pragma unroll
    for (int n = 0; n < 4; ++n){
      const int gcol = n0 + wc * 64 + n * 16 + fr;
      #pragma unroll
      for (int r = 0; r < 4; ++r){
        const int grow = grow_base + r;
        if (grow < M){
          const float v = acc[m][n][r];
          if (MODE == 0) Cb[(size_t)grow * 1024 + gcol] = f2bf(v * scale);
          else           Cf[(size_t)grow * 1024 + gcol] = v + bias[gcol] + resid[(size_t)grow * 1024 + gcol];
        }
      }
    }
  }
}

// ---------------- attention: c-split x16 (2048 blocks = 2 waves/SIMD), R10 pipeline ----------------
__global__ __launch_bounds__(64, 1) void attn_k(
    const u16* __restrict__ qp, const u16* __restrict__ kp, const u16* __restrict__ vp,
    float* __restrict__ updpart, float* __restrict__ rspart)
{
  const int bidx = blockIdx.x;
  const int c = bidx & 15, h = (bidx >> 4) & 15, b = bidx >> 8;
  const int bh = b * 16 + h;
  const int l = threadIdx.x;
  const int fr = l & 15, fg = l >> 4;

  __shared__ u16 qlds[112 * 64];
  __shared__ __align__(16) u16 vlds[2][16 * 64];   // [buf][key row 0..15][dim 0..63]

  for (int t = 0; t < 14; ++t){
    int chunk = t * 64 + l;            // 0..895
    int row = chunk >> 3, cb = chunk & 7;
    i32x4 val = {0, 0, 0, 0};
    if (row < 100)
      val = *(const i32x4*)(qp + (size_t)(b * 100 + row) * 1024 + h * 64 + cb * 8);
    *(i32x4*)((char*)qlds + row * 128 + ((cb ^ (row & 7)) * 16)) = val;
  }
  __syncthreads();

  bf16x8 qf[7][2];
  #pragma unroll
  for (int n = 0; n < 7; ++n)
    #pragma unroll
    for (int ks = 0; ks < 2; ++ks){
      int row = n * 16 + fr;
      int cb = ks * 4 + fg;
      qf[n][ks] = *(const bf16x8*)((const char*)qlds + row * 128 + ((cb ^ (row & 7)) * 16));
    }

  f32x4 acc[7][4] = {};
  float rs[7] = {};
  const f32x4 fz = {0.f, 0.f, 0.f, 0.f};
  const size_t kvbase = ((size_t)b * 4096) * 1024 + h * 64;
  const int j00 = c * 256;

  const u16* ksrc = kp + kvbase + (size_t)fr * 1024 + fg * 8;
  const u16* vsrc = vp + kvbase + (size_t)(l >> 3) * 1024 + (l & 7) * 8;  // row l>>3, chunk l&7

  auto loadK = [&](int t, bf16x8& k0, bf16x8& k1){
    const size_t ro = (size_t)(j00 + t * 16) * 1024;
    k0 = *(const bf16x8*)(ksrc + ro);
    k1 = *(const bf16x8*)(ksrc + ro + 32);
  };
  auto loadV = [&](int t, bf16x8& a, bf16x8& bb){
    const size_t ro = (size_t)(j00 + t * 16) * 1024;
    a  = *(const bf16x8*)(vsrc + ro);             // rows 0..7 of tile
    bb = *(const bf16x8*)(vsrc + ro + 8 * 1024);  // rows 8..15
  };
  auto writeV = [&](int buf, bf16x8 a, bf16x8 bb){
    *(bf16x8*)&vlds[buf][l * 8] = a;
    *(bf16x8*)&vlds[buf][512 + l * 8] = bb;
  };

  bf16x8 kc0, kc1, kn0, kn1, vn0, vn1;
  loadK(0, kc0, kc1);
  loadV(0, vn0, vn1);
  writeV(0, vn0, vn1);

  for (int t = 0; t < 16; ++t){
    const int cur = t & 1;
    if (t < 15){
      loadK(t + 1, kn0, kn1);     // issue early; latency hides under QK+softmax+PV
      loadV(t + 1, vn0, vn1);
    }

    f32x4 s[7];
    #pragma unroll
    for (int n = 0; n < 7; ++n){
      s[n] = __builtin_amdgcn_mfma_f32_16x16x32_bf16(kc0, qf[n][0], fz, 0, 0, 0);
      s[n] = __builtin_amdgcn_mfma_f32_16x16x32_bf16(kc1, qf[n][1], s[n], 0, 0, 0);
    }
    if (fr >= 4){ s[6][0] = -1e30f; s[6][1] = -1e30f; s[6][2] = -1e30f; s[6][3] = -1e30f; }

    float pv[7][4];
    #pragma unroll
    for (int r = 0; r < 4; ++r){
      float m = s[0][r];
      #pragma unroll
      for (int n = 1; n < 7; ++n) m = fmaxf(m, s[n][r]);
      m = fmaxf(m, __shfl_xor(m, 1)); m = fmaxf(m, __shfl_xor(m, 2));
      m = fmaxf(m, __shfl_xor(m, 4)); m = fmaxf(m, __shfl_xor(m, 8));
      float sum = 0.f;
      #pragma unroll
      for (int n = 0; n < 7; ++n){ float e = __expf(s[n][r] - m); pv[n][r] = e; sum += e; }
      sum += __shfl_xor(sum, 1); sum += __shfl_xor(sum, 2);
      sum += __shfl_xor(sum, 4); sum += __shfl_xor(sum, 8);
      float inv = 1.0f / sum;
      #pragma unroll
      for (int n = 0; n < 7; ++n) pv[n][r] *= inv;
    }

    bf16x4 pk[7];
    #pragma unroll
    for (int n = 0; n < 7; ++n){
      rs[n] += pv[n][0] + pv[n][1] + pv[n][2] + pv[n][3];
      bf16x4 t4;
      t4[0] = (short)f2bf(pv[n][0]); t4[1] = (short)f2bf(pv[n][1]);
      t4[2] = (short)f2bf(pv[n][2]); t4[3] = (short)f2bf(pv[n][3]);
      pk[n] = t4;
    }

    bf16x4 vf[4];
    #pragma unroll
    for (int dt = 0; dt < 4; ++dt){
      bf16x4 tv;
      #pragma unroll
      for (int jj = 0; jj < 4; ++jj)
        tv[jj] = (short)vlds[cur][(fg * 4 + jj) * 64 + dt * 16 + fr];
      vf[dt] = tv;
    }

    #pragma unroll
    for (int n = 0; n < 7; ++n)
      #pragma unroll
      for (int dt = 0; dt < 4; ++dt)
        acc[n][dt] = __builtin_amdgcn_mfma_f32_16x16x16bf16_1k(vf[dt], pk[n], acc[n][dt], 0, 0, 0);

    if (t < 15){
      writeV(cur ^ 1, vn0, vn1);   // after PV reads of vlds[cur]; other buffer anyway
      kc0 = kn0; kc1 = kn1;
    }
  }

  #pragma unroll
  for (int n = 0; n < 7; ++n){
    float v = rs[n];
    v += __shfl_xor(v, 16); v += __shfl_xor(v, 32);
    if (l < 16) rspart[((size_t)c * 128 + bh) * 112 + n * 16 + l] = v;
  }
  float* ub = updpart + ((size_t)c * 128 + bh) * 64 * 112;
  #pragma unroll
  for (int n = 0; n < 7; ++n)
    #pragma unroll
    for (int dt = 0; dt < 4; ++dt)
      #pragma unroll
      for (int r = 0; r < 4; ++r){
        int d = dt * 16 + fg * 4 + r;
        int i = n * 16 + fr;
        ub[d * 112 + i] = acc[n][dt][r];
      }
}

// ---------------- reduce 16 partials (transposed: coalesced reads) ----------------
__global__ __launch_bounds__(128) void nrm_k(const float* __restrict__ updpart,
                                             const float* __restrict__ rspart,
                                             u16* __restrict__ updn){
  const int bid = blockIdx.x;
  const int d = bid & 63, h = (bid >> 6) & 15, b = bid >> 10;
  const int bh = b * 16 + h;
  const int tid = threadIdx.x;
  const int i = (tid < 112) ? tid : 111;
  float sum = 0.f, rsum = 0.f;
  #pragma unroll
  for (int cc = 0; cc < 16; ++cc){
    sum  += updpart[(((size_t)cc * 128 + bh) * 64 + d) * 112 + i];
    rsum += rspart[((size_t)cc * 128 + bh) * 112 + i];
  }
  if (tid < 100)
    updn[((size_t)b * 100 + tid) * 1024 + h * 64 + d] = f2bf(sum / (rsum + 1e-8f));
}

// ---------------- LayerNorm over rows of resid [800 x 1024] ----------------
__global__ __launch_bounds__(256) void ln_k(const float* __restrict__ x,
                                            const float* __restrict__ g,
                                            const float* __restrict__ be,
                                            float* __restrict__ out){
  const int row = blockIdx.x;
  const int tid = threadIdx.x;
  const f4 xv = *(const f4*)(x + (size_t)row * 1024 + tid * 4);
  float s = xv[0] + xv[1] + xv[2] + xv[3];
  float q = xv[0]*xv[0] + xv[1]*xv[1] + xv[2]*xv[2] + xv[3]*xv[3];
  #pragma unroll
  for (int m = 1; m < 64; m <<= 1){ s += __shfl_xor(s, m); q += __shfl_xor(q, m); }
  __shared__ float ss[4], qq[4];
  const int w = tid >> 6;
  if ((tid & 63) == 0){ ss[w] = s; qq[w] = q; }
  __syncthreads();
  s = ss[0] + ss[1] + ss[2] + ss[3];
  q = qq[0] + qq[1] + qq[2] + qq[3];
  const float mu = s * (1.0f / 1024.0f);
  const float var = q * (1.0f / 1024.0f) - mu * mu;
  const float rstd = rsqrtf(var + 1e-5f);
  const f4 gv = *(const f4*)(g + tid * 4);
  const f4 bv = *(const f4*)(be + tid * 4);
  f4 o;
  #pragma unroll
  for (int j = 0; j < 4; ++j) o[j] = (xv[j] - mu) * rstd * gv[j] + bv[j];
  *(f4*)(out + (size_t)row * 1024 + tid * 4) = o;
}

extern "C" void kernel_launch(void* const* d_in, const int* in_sizes, int n_in,
                              void* d_out, int out_size, void* d_ws, size_t ws_size,
                              hipStream_t stream)
{
  const float* tgt   = (const float*)d_in[0];
  const float* mem   = (const float*)d_in[1];
  const float* mpos  = (const float*)d_in[2];
  const float* qpos  = (const float*)d_in[3];
  const float* Wq    = (const float*)d_in[4];
  const float* Wk    = (const float*)d_in[5];
  const float* Wv    = (const float*)d_in[6];
  const float* Wo    = (const float*)d_in[7];
  const float* bo    = (const float*)d_in[8];
  const float* gamma = (const float*)d_in[9];
  const float* beta  = (const float*)d_in[10];

  char* ws = (char*)d_ws;
  u16* qA     = (u16*)(ws + 0);
  u16* Wbf    = (u16*)(ws + 1638400);
  u16* kA     = (u16*)(ws + 10027008);
  u16* vA     = (u16*)(ws + 77135872);
  u16* qproj  = (u16*)(ws + 144244736);
  u16* kproj  = (u16*)(ws + 145883136);
  u16* vproj  = kA;                                   // kA dead after K-GEMM (serialized)
  // post-GEMM region reuse (vA dead after V-GEMM): 16-way partials
  float* updpart = (float*)(ws + 77135872);                       // 58,720,256 B
  float* rspart  = (float*)(ws + 77135872 + 58720256);            //    917,504 B
  u16*   updn    = (u16*)  (ws + 77135872 + 59637760);            //  1,638,400 B
  float* resid   = (float*)(ws + 77135872 + 61276160);            //  3,276,800 B (total 64.55MB < 67.1MB)

  prep_all<<<8992, 256, 0, stream>>>(mem, mpos, tgt, qpos, Wq, Wk, Wv, Wo, kA, vA, qA, Wbf);
  gemm_bt<0><<<56, 256, 0, stream>>>(qA, Wbf, qproj, nullptr, nullptr, nullptr, 800, 0.125f);
  gemm256<<<512, 512, 0, stream>>>(kA, Wbf + 1048576, kproj);
  gemm256<<<512, 512, 0, stream>>>(vA, Wbf + 2097152, vproj);
  attn_k<<<2048, 64, 0, stream>>>(qproj, kproj, vproj, updpart, rspart);
  nrm_k<<<8192, 128, 0, stream>>>(updpart, rspart, updn);
  gemm_bt<1><<<56, 256, 0, stream>>>(updn, Wbf + 3145728, nullptr, resid, bo, tgt, 800, 1.0f);
  ln_k<<<800, 256, 0, stream>>>(resid, gamma, beta, (float*)d_out);
}

// Round 17
// 363.529 us; speedup vs baseline: 1.3102x; 1.0382x over previous
//
#include <hip/hip_runtime.h>

typedef unsigned short u16;
typedef __attribute__((ext_vector_type(8))) short bf16x8;
typedef __attribute__((ext_vector_type(4))) short bf16x4;
typedef __attribute__((ext_vector_type(4))) float f32x4;
typedef __attribute__((ext_vector_type(4))) unsigned short u16x4;
typedef __attribute__((ext_vector_type(8))) unsigned short u16x8;
typedef __attribute__((ext_vector_type(4))) int i32x4;
typedef __attribute__((ext_vector_type(4))) float f4;

#define DI __device__ __forceinline__

// B=8, Q=100, C=1024, K=4096, NH=16, HD=64, SCALE=0.125

DI u16 f2bf(float f){
  unsigned int u = __float_as_uint(f);
  return (u16)((u + 0x7FFFu + ((u >> 16) & 1u)) >> 16);
}

DI void gl_lds16(const void* g, void* l){
  __builtin_amdgcn_global_load_lds((const __attribute__((address_space(1))) unsigned int*)g,
                                   (__attribute__((address_space(3))) unsigned int*)l, 16, 0, 0);
}

// ---------------- fused prep: blocks 0..4095 = kv (R4 form), 4096..8991 = q/W ----------------
__global__ __launch_bounds__(256) void prep_all(const float* __restrict__ mem,
                                                const float* __restrict__ mpos,
                                                const float* __restrict__ tgt,
                                                const float* __restrict__ qpos,
                                                const float* __restrict__ Wq, const float* __restrict__ Wk,
                                                const float* __restrict__ Wv, const float* __restrict__ Wo,
                                                u16* __restrict__ kA, u16* __restrict__ vA,
                                                u16* __restrict__ qA, u16* __restrict__ Wbf){
  if (blockIdx.x < 4096){
    const int t = blockIdx.x * 256 + threadIdx.x;      // 1,048,576 threads
    #pragma unroll
    for (int i = 0; i < 4; ++i){
      const size_t g = (size_t)t + (size_t)i * 1048576; // 8-float group id, 4,194,304 total
      f4 m0 = __builtin_nontemporal_load((const f4*)mem  + g * 2);
      f4 m1 = __builtin_nontemporal_load((const f4*)mem  + g * 2 + 1);
      f4 p0 = __builtin_nontemporal_load((const f4*)mpos + g * 2);
      f4 p1 = __builtin_nontemporal_load((const f4*)mpos + g * 2 + 1);
      u16x8 k, v;
      #pragma unroll
      for (int j = 0; j < 4; ++j){
        k[j]     = f2bf(m0[j] + p0[j]);  v[j]     = f2bf(m0[j]);
        k[j + 4] = f2bf(m1[j] + p1[j]);  v[j + 4] = f2bf(m1[j]);
      }
      ((u16x8*)kA)[g] = k;
      ((u16x8*)vA)[g] = v;
    }
  } else {
    int gid = (blockIdx.x - 4096) * 256 + threadIdx.x;  // 4896*256 = 1,253,376
    const int NQ4 = 819200 / 4;                // 204800
    if (gid < NQ4){
      f4 a = ((const f4*)tgt)[gid];
      f4 b = ((const f4*)qpos)[gid];
      u16x4 r;
      #pragma unroll
      for (int j = 0; j < 4; ++j) r[j] = f2bf(a[j] + b[j]);
      ((u16x4*)qA)[gid] = r;
    } else {
      int wid = gid - NQ4;                     // 0..1048575
      int sel = wid >> 18;                     // /262144
      int off = wid & 262143;
      const float* W = (sel == 0) ? Wq : (sel == 1) ? Wk : (sel == 2) ? Wv : Wo;
      f4 w = ((const f4*)W)[off];
      u16x4 r;
      #pragma unroll
      for (int j = 0; j < 4; ++j) r[j] = f2bf(w[j]);
      ((u16x4*)(Wbf))[(size_t)sel * 262144 + off] = r;
    }
  }
}

// ---------------- 256x256 8-wave GEMM (R7/R12 4-phase version, replay-proven) ----------------
DI void gemm256_body(const u16* __restrict__ A, const u16* __restrict__ Bw,
                     u16* __restrict__ Cb, float scale, int sbid, int tid, char* lds)
{
  const int l = tid & 63, w = tid >> 6;
  const int mb = sbid >> 2, nb = sbid & 3;
  const int m0 = mb * 256, n0 = nb * 256;
  const int fr = l & 15, fg = l >> 4;
  const int wm = w >> 2, wn = w & 3;

  char* ldsA  = lds + wm * 8192 + l * 16;
  char* ldsB  = lds + 32768 + wn * 4096 + l * 16;
  char* ldsS0 = lds + w * 1024;
  char* ldsS1 = lds + (8 + w) * 1024;
  const u16* gA0 = A  + (size_t)(m0 + w * 16 + fr) * 1024 + fg * 8;
  const u16* gA1 = A  + (size_t)(m0 + (8 + w) * 16 + fr) * 1024 + fg * 8;
  const u16* gB0 = Bw + (size_t)(n0 + w * 16 + fr) * 1024 + fg * 8;
  const u16* gB1 = Bw + (size_t)(n0 + (8 + w) * 16 + fr) * 1024 + fg * 8;

  auto stA = [&](int pp, int kh, int kt){
    const int o = kt * 64 + kh * 32;
    gl_lds16(gA0 + o, ldsS0 + pp * 65536 + kh * 16384);
    gl_lds16(gA1 + o, ldsS1 + pp * 65536 + kh * 16384);
  };
  auto stB = [&](int pp, int kh, int kt){
    const int o = kt * 64 + kh * 32;
    gl_lds16(gB0 + o, ldsS0 + pp * 65536 + 32768 + kh * 16384);
    gl_lds16(gB1 + o, ldsS1 + pp * 65536 + 32768 + kh * 16384);
  };
  auto rdA4 = [&](bf16x8* av, int pp, int kh, int mfb){
    #pragma unroll
    for (int i = 0; i < 4; ++i)
      av[i] = *(const bf16x8*)(ldsA + pp * 65536 + kh * 16384 + (mfb + i) * 1024);
  };
  auto rdB4 = [&](bf16x8* bv, int pp, int kh){
    #pragma unroll
    for (int i = 0; i < 4; ++i)
      bv[i] = *(const bf16x8*)(ldsB + pp * 65536 + kh * 16384 + i * 1024);
  };

  f32x4 acc[8][4] = {};

  stA(0, 0, 0); stB(0, 0, 0); stA(0, 1, 0); stB(0, 1, 0);
  stA(1, 0, 1); stB(1, 0, 1);
  asm volatile("s_waitcnt vmcnt(8)" ::: "memory");
  __builtin_amdgcn_s_barrier();

  auto ktbody = [&](int P, int kt){
    const int kt1 = (kt + 1 > 15) ? 15 : kt + 1;
    const int kt2 = (kt + 2 > 15) ? 15 : kt + 2;
    bf16x8 av[4], bv[4];

    rdA4(av, P, 0, 0); rdB4(bv, P, 0);
    stA(P ^ 1, 1, kt1);
    __builtin_amdgcn_s_barrier();
    __builtin_amdgcn_s_setprio(1);
    #pragma unroll
    for (int i = 0; i < 4; ++i)
      #pragma unroll
      for (int n = 0; n < 4; ++n)
        acc[i][n] = __builtin_amdgcn_mfma_f32_16x16x32_bf16(av[i], bv[n], acc[i][n], 0, 0, 0);
    __builtin_amdgcn_s_setprio(0);
    __builtin_amdgcn_s_barrier();

    rdA4(av, P, 0, 4);
    stB(P ^ 1, 1, kt1);
    asm volatile("s_waitcnt vmcnt(8)" ::: "memory");
    __builtin_amdgcn_s_barrier();
    __builtin_amdgcn_s_setprio(1);
    #pragma unroll
    for (int i = 0; i < 4; ++i)
      #pragma unroll
      for (int n = 0; n < 4; ++n)
        acc[4 + i][n] = __builtin_amdgcn_mfma_f32_16x16x32_bf16(av[i], bv[n], acc[4 + i][n], 0, 0, 0);
    __builtin_amdgcn_s_setprio(0);
    __builtin_amdgcn_s_barrier();

    rdA4(av, P, 1, 0); rdB4(bv, P, 1);
    stA(P, 0, kt2);
    __builtin_amdgcn_s_barrier();
    __builtin_amdgcn_s_setprio(1);
    #pragma unroll
    for (int i = 0; i < 4; ++i)
      #pragma unroll
      for (int n = 0; n < 4; ++n)
        acc[i][n] = __builtin_amdgcn_mfma_f32_16x16x32_bf16(av[i], bv[n], acc[i][n], 0, 0, 0);
    __builtin_amdgcn_s_setprio(0);
    __builtin_amdgcn_s_barrier();

    rdA4(av, P, 1, 4);
    stB(P, 0, kt2);
    asm volatile("s_waitcnt vmcnt(8)" ::: "memory");
    __builtin_amdgcn_s_barrier();
    __builtin_amdgcn_s_setprio(1);
    #pragma unroll
    for (int i = 0; i < 4; ++i)
      #pragma unroll
      for (int n = 0; n < 4; ++n)
        acc[4 + i][n] = __builtin_amdgcn_mfma_f32_16x16x32_bf16(av[i], bv[n], acc[4 + i][n], 0, 0, 0);
    __builtin_amdgcn_s_setprio(0);
    __builtin_amdgcn_s_barrier();
  };

  for (int kk = 0; kk < 8; ++kk){
    ktbody(0, 2 * kk);
    ktbody(1, 2 * kk + 1);
  }

  asm volatile("s_waitcnt vmcnt(0)" ::: "memory");

  #pragma unroll
  for (int mf = 0; mf < 8; ++mf){
    #pragma unroll
    for (int nf = 0; nf < 4; ++nf){
      const int gcol = n0 + wn * 64 + nf * 16 + fr;
      #pragma unroll
      for (int r = 0; r < 4; ++r){
        const int grow = m0 + wm * 128 + mf * 16 + fg * 4 + r;
        Cb[(size_t)grow * 1024 + gcol] = f2bf(acc[mf][nf][r] * scale);
      }
    }
  }
}

__global__ __launch_bounds__(512, 1) void gemm256(
    const u16* __restrict__ A, const u16* __restrict__ Bw, u16* __restrict__ Cb)
{
  __shared__ __align__(16) char lds[131072];
  const int nwg = gridDim.x;
  const int sbid = (blockIdx.x & 7) * (nwg >> 3) + (blockIdx.x >> 3);
  gemm256_body(A, Bw, Cb, 1.0f, sbid, threadIdx.x, lds);
}

// ---------------- 128x128 GEMM (small M; R1 coalesced-stage layout) ----------------
template<int MODE>
__global__ __launch_bounds__(256, 2) void gemm_bt(
    const u16* __restrict__ A, const u16* __restrict__ Bw,
    u16* __restrict__ Cb, float* __restrict__ Cf,
    const float* __restrict__ bias, const float* __restrict__ resid,
    int M, float scale)
{
  __shared__ u16 lA[2][128 * 32];
  __shared__ u16 lB[2][128 * 32];
  const int tid = threadIdx.x;
  const int l = tid & 63, w = tid >> 6;
  const int nwg = gridDim.x;
  int bid = blockIdx.x;
  bid = (bid & 7) * (nwg >> 3) + (bid >> 3);   // XCD swizzle (nwg % 8 == 0 always)
  const int mb = bid >> 3, nb = bid & 7;
  const int m0 = mb * 128, n0 = nb * 128;
  const int fr = l & 15, fg = l >> 4;
  const int wr = w >> 1, wc = w & 1;

  f32x4 acc[4][4] = {};

  auto stage = [&](int buf, int kt){
    const int k0 = kt * 32;
    #pragma unroll
    for (int q = 0; q < 2; ++q){
      int r = w * 32 + q * 16 + (l >> 2);
      int ar = m0 + r; if (ar >= M) ar = M - 1;
      gl_lds16(A  + (size_t)ar * 1024 + k0 + (l & 3) * 8, &lA[buf][(w * 32 + q * 16) * 32]);
      gl_lds16(Bw + (size_t)(n0 + r) * 1024 + k0 + (l & 3) * 8, &lB[buf][(w * 32 + q * 16) * 32]);
    }
  };

  stage(0, 0);
  __syncthreads();
  for (int kt = 0; kt < 32; ++kt){
    const int cur = kt & 1;
    if (kt < 31) stage(cur ^ 1, kt + 1);
    bf16x8 av[4], bv[4];
    #pragma unroll
    for (int m = 0; m < 4; ++m)
      av[m] = *(const bf16x8*)&lA[cur][(wr * 64 + m * 16 + fr) * 32 + fg * 8];
    #pragma unroll
    for (int n = 0; n < 4; ++n)
      bv[n] = *(const bf16x8*)&lB[cur][(wc * 64 + n * 16 + fr) * 32 + fg * 8];
    #pragma unroll
    for (int m = 0; m < 4; ++m)
      #pragma unroll
      for (int n = 0; n < 4; ++n)
        acc[m][n] = __builtin_amdgcn_mfma_f32_16x16x32_bf16(av[m], bv[n], acc[m][n], 0, 0, 0);
    __syncthreads();
  }

  #pragma unroll
  for (int m = 0; m < 4; ++m){
    const int grow_base = m0 + wr * 64 + m * 16 + fg * 4;
    #pragma unroll
    for (int n = 0; n < 4; ++n){
      const int gcol = n0 + wc * 64 + n * 16 + fr;
      #pragma unroll
      for (int r = 0; r < 4; ++r){
        const int grow = grow_base + r;
        if (grow < M){
          const float v = acc[m][n][r];
          if (MODE == 0) Cb[(size_t)grow * 1024 + gcol] = f2bf(v * scale);
          else           Cf[(size_t)grow * 1024 + gcol] = v + bias[gcol] + resid[(size_t)grow * 1024 + gcol];
        }
      }
    }
  }
}

// ---------------- attention (best measured: x8 c-split, single wave, reg-staged V) ----------------
__global__ __launch_bounds__(64, 1) void attn_k(
    const u16* __restrict__ qp, const u16* __restrict__ kp, const u16* __restrict__ vp,
    float* __restrict__ updpart, float* __restrict__ rspart)
{
  const int bidx = blockIdx.x;
  const int c = bidx & 7, h = (bidx >> 3) & 15, b = bidx >> 7;
  const int bh = b * 16 + h;
  const int l = threadIdx.x;
  const int fr = l & 15, fg = l >> 4;

  __shared__ u16 qlds[112 * 64];
  __shared__ __align__(16) u16 vlds[2][16 * 64];   // [buf][key row 0..15][dim 0..63]

  for (int t = 0; t < 14; ++t){
    int chunk = t * 64 + l;            // 0..895
    int row = chunk >> 3, cb = chunk & 7;
    i32x4 val = {0, 0, 0, 0};
    if (row < 100)
      val = *(const i32x4*)(qp + (size_t)(b * 100 + row) * 1024 + h * 64 + cb * 8);
    *(i32x4*)((char*)qlds + row * 128 + ((cb ^ (row & 7)) * 16)) = val;
  }
  __syncthreads();

  bf16x8 qf[7][2];
  #pragma unroll
  for (int n = 0; n < 7; ++n)
    #pragma unroll
    for (int ks = 0; ks < 2; ++ks){
      int row = n * 16 + fr;
      int cb = ks * 4 + fg;
      qf[n][ks] = *(const bf16x8*)((const char*)qlds + row * 128 + ((cb ^ (row & 7)) * 16));
    }

  f32x4 acc[7][4] = {};
  float rs[7] = {};
  const f32x4 fz = {0.f, 0.f, 0.f, 0.f};
  const size_t kvbase = ((size_t)b * 4096) * 1024 + h * 64;
  const int j00 = c * 512;

  const u16* ksrc = kp + kvbase + (size_t)fr * 1024 + fg * 8;
  const u16* vsrc = vp + kvbase + (size_t)(l >> 3) * 1024 + (l & 7) * 8;  // row l>>3, chunk l&7

  auto loadK = [&](int t, bf16x8& k0, bf16x8& k1){
    const size_t ro = (size_t)(j00 + t * 16) * 1024;
    k0 = *(const bf16x8*)(ksrc + ro);
    k1 = *(const bf16x8*)(ksrc + ro + 32);
  };
  auto loadV = [&](int t, bf16x8& a, bf16x8& bb){
    const size_t ro = (size_t)(j00 + t * 16) * 1024;
    a  = *(const bf16x8*)(vsrc + ro);             // rows 0..7 of tile
    bb = *(const bf16x8*)(vsrc + ro + 8 * 1024);  // rows 8..15
  };
  auto writeV = [&](int buf, bf16x8 a, bf16x8 bb){
    *(bf16x8*)&vlds[buf][l * 8] = a;
    *(bf16x8*)&vlds[buf][512 + l * 8] = bb;
  };

  bf16x8 kc0, kc1, kn0, kn1, vn0, vn1;
  loadK(0, kc0, kc1);
  loadV(0, vn0, vn1);
  writeV(0, vn0, vn1);

  for (int t = 0; t < 32; ++t){
    const int cur = t & 1;
    if (t < 31){
      loadK(t + 1, kn0, kn1);     // issue early; latency hides under QK+softmax+PV
      loadV(t + 1, vn0, vn1);
    }

    f32x4 s[7];
    #pragma unroll
    for (int n = 0; n < 7; ++n){
      s[n] = __builtin_amdgcn_mfma_f32_16x16x32_bf16(kc0, qf[n][0], fz, 0, 0, 0);
      s[n] = __builtin_amdgcn_mfma_f32_16x16x32_bf16(kc1, qf[n][1], s[n], 0, 0, 0);
    }
    if (fr >= 4){ s[6][0] = -1e30f; s[6][1] = -1e30f; s[6][2] = -1e30f; s[6][3] = -1e30f; }

    float pv[7][4];
    #pragma unroll
    for (int r = 0; r < 4; ++r){
      float m = s[0][r];
      #pragma unroll
      for (int n = 1; n < 7; ++n) m = fmaxf(m, s[n][r]);
      m = fmaxf(m, __shfl_xor(m, 1)); m = fmaxf(m, __shfl_xor(m, 2));
      m = fmaxf(m, __shfl_xor(m, 4)); m = fmaxf(m, __shfl_xor(m, 8));
      float sum = 0.f;
      #pragma unroll
      for (int n = 0; n < 7; ++n){ float e = __expf(s[n][r] - m); pv[n][r] = e; sum += e; }
      sum += __shfl_xor(sum, 1); sum += __shfl_xor(sum, 2);
      sum += __shfl_xor(sum, 4); sum += __shfl_xor(sum, 8);
      float inv = 1.0f / sum;
      #pragma unroll
      for (int n = 0; n < 7; ++n) pv[n][r] *= inv;
    }

    bf16x4 pk[7];
    #pragma unroll
    for (int n = 0; n < 7; ++n){
      rs[n] += pv[n][0] + pv[n][1] + pv[n][2] + pv[n][3];
      bf16x4 t4;
      t4[0] = (short)f2bf(pv[n][0]); t4[1] = (short)f2bf(pv[n][1]);
      t4[2] = (short)f2bf(pv[n][2]); t4[3] = (short)f2bf(pv[n][3]);
      pk[n] = t4;
    }

    bf16x4 vf[4];
    #pragma unroll
    for (int dt = 0; dt < 4; ++dt){
      bf16x4 tv;
      #pragma unroll
      for (int jj = 0; jj < 4; ++jj)
        tv[jj] = (short)vlds[cur][(fg * 4 + jj) * 64 + dt * 16 + fr];
      vf[dt] = tv;
    }

    #pragma unroll
    for (int n = 0; n < 7; ++n)
      #pragma unroll
      for (int dt = 0; dt < 4; ++dt)
        acc[n][dt] = __builtin_amdgcn_mfma_f32_16x16x16bf16_1k(vf[dt], pk[n], acc[n][dt], 0, 0, 0);

    if (t < 31){
      writeV(cur ^ 1, vn0, vn1);   // after PV reads of vlds[cur]; other buffer anyway
      kc0 = kn0; kc1 = kn1;
    }
  }

  #pragma unroll
  for (int n = 0; n < 7; ++n){
    float v = rs[n];
    v += __shfl_xor(v, 16); v += __shfl_xor(v, 32);
    if (l < 16) rspart[((size_t)c * 128 + bh) * 112 + n * 16 + l] = v;
  }
  float* ub = updpart + ((size_t)c * 128 + bh) * 64 * 112;
  #pragma unroll
  for (int n = 0; n < 7; ++n)
    #pragma unroll
    for (int dt = 0; dt < 4; ++dt)
      #pragma unroll
      for (int r = 0; r < 4; ++r){
        int d = dt * 16 + fg * 4 + r;
        int i = n * 16 + fr;
        ub[d * 112 + i] = acc[n][dt][r];
      }
}

// ---------------- reduce partials (transposed: coalesced reads) ----------------
__global__ __launch_bounds__(128) void nrm_k(const float* __restrict__ updpart,
                                             const float* __restrict__ rspart,
                                             u16* __restrict__ updn){
  const int bid = blockIdx.x;
  const int d = bid & 63, h = (bid >> 6) & 15, b = bid >> 10;
  const int bh = b * 16 + h;
  const int tid = threadIdx.x;
  const int i = (tid < 112) ? tid : 111;
  float sum = 0.f, rsum = 0.f;
  #pragma unroll
  for (int cc = 0; cc < 8; ++cc){
    sum  += updpart[(((size_t)cc * 128 + bh) * 64 + d) * 112 + i];
    rsum += rspart[((size_t)cc * 128 + bh) * 112 + i];
  }
  if (tid < 100)
    updn[((size_t)b * 100 + tid) * 1024 + h * 64 + d] = f2bf(sum / (rsum + 1e-8f));
}

// ---------------- LayerNorm over rows of resid [800 x 1024] ----------------
__global__ __launch_bounds__(256) void ln_k(const float* __restrict__ x,
                                            const float* __restrict__ g,
                                            const float* __restrict__ be,
                                            float* __restrict__ out){
  const int row = blockIdx.x;
  const int tid = threadIdx.x;
  const f4 xv = *(const f4*)(x + (size_t)row * 1024 + tid * 4);
  float s = xv[0] + xv[1] + xv[2] + xv[3];
  float q = xv[0]*xv[0] + xv[1]*xv[1] + xv[2]*xv[2] + xv[3]*xv[3];
  #pragma unroll
  for (int m = 1; m < 64; m <<= 1){ s += __shfl_xor(s, m); q += __shfl_xor(q, m); }
  __shared__ float ss[4], qq[4];
  const int w = tid >> 6;
  if ((tid & 63) == 0){ ss[w] = s; qq[w] = q; }
  __syncthreads();
  s = ss[0] + ss[1] + ss[2] + ss[3];
  q = qq[0] + qq[1] + qq[2] + qq[3];
  const float mu = s * (1.0f / 1024.0f);
  const float var = q * (1.0f / 1024.0f) - mu * mu;
  const float rstd = rsqrtf(var + 1e-5f);
  const f4 gv = *(const f4*)(g + tid * 4);
  const f4 bv = *(const f4*)(be + tid * 4);
  f4 o;
  #pragma unroll
  for (int j = 0; j < 4; ++j) o[j] = (xv[j] - mu) * rstd * gv[j] + bv[j];
  *(f4*)(out + (size_t)row * 1024 + tid * 4) = o;
}

extern "C" void kernel_launch(void* const* d_in, const int* in_sizes, int n_in,
                              void* d_out, int out_size, void* d_ws, size_t ws_size,
                              hipStream_t stream)
{
  const float* tgt   = (const float*)d_in[0];
  const float* mem   = (const float*)d_in[1];
  const float* mpos  = (const float*)d_in[2];
  const float* qpos  = (const float*)d_in[3];
  const float* Wq    = (const float*)d_in[4];
  const float* Wk    = (const float*)d_in[5];
  const float* Wv    = (const float*)d_in[6];
  const float* Wo    = (const float*)d_in[7];
  const float* bo    = (const float*)d_in[8];
  const float* gamma = (const float*)d_in[9];
  const float* beta  = (const float*)d_in[10];

  char* ws = (char*)d_ws;
  u16* qA     = (u16*)(ws + 0);
  u16* Wbf    = (u16*)(ws + 1638400);
  u16* kA     = (u16*)(ws + 10027008);
  u16* vA     = (u16*)(ws + 77135872);
  u16* qproj  = (u16*)(ws + 144244736);
  u16* kproj  = (u16*)(ws + 145883136);
  u16* vproj  = kA;                                   // kA dead after K-GEMM (serialized)
  float* updpart = (float*)(ws + 77135872);           // vA dead after V-GEMM
  float* rspart  = (float*)(ws + 77135872 + 29360128);
  u16*   updn    = (u16*)  (ws + 77135872 + 29818880);
  float* resid   = (float*)(ws + 77135872 + 31457280);

  prep_all<<<8992, 256, 0, stream>>>(mem, mpos, tgt, qpos, Wq, Wk, Wv, Wo, kA, vA, qA, Wbf);
  gemm_bt<0><<<56, 256, 0, stream>>>(qA, Wbf, qproj, nullptr, nullptr, nullptr, 800, 0.125f);
  gemm256<<<512, 512, 0, stream>>>(kA, Wbf + 1048576, kproj);
  gemm256<<<512, 512, 0, stream>>>(vA, Wbf + 2097152, vproj);
  attn_k<<<1024, 64, 0, stream>>>(qproj, kproj, vproj, updpart, rspart);
  nrm_k<<<8192, 128, 0, stream>>>(updpart, rspart, updn);
  gemm_bt<1><<<56, 256, 0, stream>>>(updn, Wbf + 3145728, nullptr, resid, bo, tgt, 800, 1.0f);
  ln_k<<<800, 256, 0, stream>>>(resid, gamma, beta, (float*)d_out);
}